// Round 8
// baseline (293.030 us; speedup 1.0000x reference)
//
#include <hip/hip_runtime.h>

// Problem constants
#define B_SZ   4
#define NTOK   5440
#define MTOT   (B_SZ*NTOK)   // 21760
#define DMODEL 256
#define FFDIM  1024
#define NROWP  (MTOT/128)    // 170 row panels

typedef __attribute__((ext_vector_type(8))) __bf16 bf16x8;
typedef __attribute__((ext_vector_type(4))) float  f32x4;

static __device__ __forceinline__ unsigned short f2b(float f) {
    unsigned u = __builtin_bit_cast(unsigned, f);
    u = (u + 0x7FFF + ((u >> 16) & 1)) >> 16;     // RNE (finite inputs)
    return (unsigned short)u;
}
static __device__ __forceinline__ float b2f(unsigned short s) {
    return __builtin_bit_cast(float, (unsigned)s << 16);
}
static __device__ __forceinline__ float lo_bf(unsigned u) {
    return __builtin_bit_cast(float, u << 16);
}
static __device__ __forceinline__ float hi_bf(unsigned u) {
    return __builtin_bit_cast(float, u & 0xffff0000u);
}
static __device__ __forceinline__ unsigned pk2(float lo, float hi) {
    return (unsigned)f2b(lo) | ((unsigned)f2b(hi) << 16);
}
static __device__ __forceinline__ uint4 cvt8(const float4 a, const float4 b) {
    uint4 u;
    u.x = pk2(a.x, a.y); u.y = pk2(a.z, a.w);
    u.z = pk2(b.x, b.y); u.w = pk2(b.z, b.w);
    return u;
}

// ---------------------------------------------------------------------------
// qkv GEMM, fully fused input conversion. A = src (c<2) or src+pos (c>=2),
// both fp32; W = w_value / w_off / w_attn fp32. 128x128 tile, BK=32,
// single-barrier LDS double-buffer: loads issued AFTER the barrier overlap
// the MFMA phase; ds_write waits only its own loads' vmcnt.
// Grid 8*5*22 swizzled (xcd = id&7).
// ---------------------------------------------------------------------------
__global__ __launch_bounds__(256)
void qkv_gemm(const float* __restrict__ src, const float* __restrict__ pos,
              const float* __restrict__ w_value, const float* __restrict__ w_off,
              const float* __restrict__ w_attn,
              const float* __restrict__ b_value,
              const float* __restrict__ b_off, const float* __restrict__ b_attn,
              const unsigned char* __restrict__ rowmask,
              unsigned short* __restrict__ value_b, unsigned short* __restrict__ oa_b)
{
    const int K = 256;
    const int id  = blockIdx.x;
    const int xcd = id & 7;
    const int j   = id >> 3;
    const int c   = j % 5;
    const int r   = 8 * (j / 5) + xcd;
    if (r >= NROWP) return;
    const int row0 = r * 128;
    const bool isv = (c < 2);
    const float* Wp;
    int col0;
    if (isv)          { Wp = w_value + (size_t)(c * 128) * 256;       col0 = c * 128; }
    else if (c < 4)   { Wp = w_off   + (size_t)((c - 2) * 128) * 256; col0 = (c - 2) * 128; }
    else              { Wp = w_attn;                                  col0 = 256; }
    unsigned short* C = isv ? value_b : oa_b;
    const int ldc = isv ? 256 : 384;

    __shared__ unsigned short As[2][128 * 32];
    __shared__ unsigned short Bs[2][128 * 32];
    const int tid  = threadIdx.x;
    const int lane = tid & 63;
    const int wave = tid >> 6;
    const int wr = (wave >> 1) * 64, wc = (wave & 1) * 64;
    const int mrow = lane & 15, quad = lane >> 4;

    const int ri = tid >> 1, ki = (tid & 1) * 16;   // stage row / k-offset
    const float* Ap = src + (size_t)(row0 + ri) * 256 + ki;
    const float* Pp = pos + (size_t)(row0 + ri) * 256 + ki;
    const float* Bp = Wp  + (size_t)ri * 256 + ki;

    f32x4 acc[4][4] = {};
    float4 a[4], b[4];

    // prefetch k=0
    #pragma unroll
    for (int q = 0; q < 4; ++q) {
        a[q] = ((const float4*)Ap)[q];
        b[q] = ((const float4*)Bp)[q];
    }
    if (!isv) {
        #pragma unroll
        for (int q = 0; q < 4; ++q) {
            const float4 p = ((const float4*)Pp)[q];
            a[q].x += p.x; a[q].y += p.y; a[q].z += p.z; a[q].w += p.w;
        }
    }

    int ib = 0;
    for (int k0 = 0; k0 < K; k0 += 32, ib ^= 1) {
        // stage (waits vmcnt for a/b loads only)
        *(uint4*)&As[ib][ri * 32 + ki]     = cvt8(a[0], a[1]);
        *(uint4*)&As[ib][ri * 32 + ki + 8] = cvt8(a[2], a[3]);
        *(uint4*)&Bs[ib][ri * 32 + ki]     = cvt8(b[0], b[1]);
        *(uint4*)&Bs[ib][ri * 32 + ki + 8] = cvt8(b[2], b[3]);
        __syncthreads();
        if (k0 + 32 < K) {
            #pragma unroll
            for (int q = 0; q < 4; ++q) {
                a[q] = ((const float4*)(Ap + k0 + 32))[q];
                b[q] = ((const float4*)(Bp + k0 + 32))[q];
            }
            if (!isv) {
                #pragma unroll
                for (int q = 0; q < 4; ++q) {
                    const float4 p = ((const float4*)(Pp + k0 + 32))[q];
                    a[q].x += p.x; a[q].y += p.y; a[q].z += p.z; a[q].w += p.w;
                }
            }
        }
        bf16x8 af[4], bfr[4];
        #pragma unroll
        for (int t4 = 0; t4 < 4; ++t4) {
            af[t4]  = *(const bf16x8*)&As[ib][(wr + t4 * 16 + mrow) * 32 + quad * 8];
            bfr[t4] = *(const bf16x8*)&Bs[ib][(wc + t4 * 16 + mrow) * 32 + quad * 8];
        }
        #pragma unroll
        for (int ti = 0; ti < 4; ++ti)
            #pragma unroll
            for (int tj = 0; tj < 4; ++tj)
                acc[ti][tj] = __builtin_amdgcn_mfma_f32_16x16x32_bf16(
                                  bfr[tj], af[ti], acc[ti][tj], 0, 0, 0);
    }

    // swapped layout: row = ..+mrow, col = ..+quad*4+r ; ushort4 stores
    #pragma unroll
    for (int ti = 0; ti < 4; ++ti) {
        const int row = row0 + wr + ti * 16 + mrow;
        const bool msk = isv && rowmask[row];
        #pragma unroll
        for (int tj = 0; tj < 4; ++tj) {
            const int col = col0 + wc + tj * 16 + quad * 4;
            const float4 bv = isv ? *(const float4*)(b_value + col)
                            : (col < 256 ? *(const float4*)(b_off + col)
                                         : *(const float4*)(b_attn + col - 256));
            ushort4 o;
            o.x = msk ? 0 : f2b(acc[ti][tj][0] + bv.x);
            o.y = msk ? 0 : f2b(acc[ti][tj][1] + bv.y);
            o.z = msk ? 0 : f2b(acc[ti][tj][2] + bv.z);
            o.w = msk ? 0 : f2b(acc[ti][tj][3] + bv.w);
            *(ushort4*)(C + (size_t)row * ldc + col) = o;
        }
    }
}

// ---------------------------------------------------------------------------
// FFN1: C = relu(A @ W^T + bias) bf16; A bf16 [M,256], W fp32 [1024,256].
// 128x128 tile, BK=32, single-barrier dbuf, grid 8*8*22 swizzled.
// ---------------------------------------------------------------------------
__global__ __launch_bounds__(256)
void ffn1_gemm(const unsigned short* __restrict__ A,
               const float* __restrict__ W, const float* __restrict__ bias,
               unsigned short* __restrict__ Cb)
{
    const int K = 256, Nout = 1024;
    const int id  = blockIdx.x;
    const int xcd = id & 7;
    const int j   = id >> 3;
    const int c   = j & 7;
    const int r   = 8 * (j >> 3) + xcd;
    if (r >= NROWP) return;
    const int row0 = r * 128, col0 = c * 128;

    __shared__ unsigned short As[2][128 * 32];
    __shared__ unsigned short Bs[2][128 * 32];
    const int tid  = threadIdx.x;
    const int lane = tid & 63;
    const int wave = tid >> 6;
    const int wr = (wave >> 1) * 64, wc = (wave & 1) * 64;
    const int mrow = lane & 15, quad = lane >> 4;

    const int ri = tid >> 1, ki = (tid & 1) * 16;
    const unsigned short* Ap = A + (size_t)(row0 + ri) * K + ki;
    const float* Bp = W + (size_t)(col0 + ri) * K + ki;

    f32x4 acc[4][4] = {};
    uint4 ua0, ua1; float4 b[4];
    ua0 = ((const uint4*)Ap)[0]; ua1 = ((const uint4*)Ap)[1];
    #pragma unroll
    for (int q = 0; q < 4; ++q) b[q] = ((const float4*)Bp)[q];

    int ib = 0;
    for (int k0 = 0; k0 < K; k0 += 32, ib ^= 1) {
        *(uint4*)&As[ib][ri * 32 + ki]     = ua0;
        *(uint4*)&As[ib][ri * 32 + ki + 8] = ua1;
        *(uint4*)&Bs[ib][ri * 32 + ki]     = cvt8(b[0], b[1]);
        *(uint4*)&Bs[ib][ri * 32 + ki + 8] = cvt8(b[2], b[3]);
        __syncthreads();
        if (k0 + 32 < K) {
            ua0 = ((const uint4*)(Ap + k0 + 32))[0];
            ua1 = ((const uint4*)(Ap + k0 + 32))[1];
            #pragma unroll
            for (int q = 0; q < 4; ++q) b[q] = ((const float4*)(Bp + k0 + 32))[q];
        }
        bf16x8 af[4], bfr[4];
        #pragma unroll
        for (int t4 = 0; t4 < 4; ++t4) {
            af[t4]  = *(const bf16x8*)&As[ib][(wr + t4 * 16 + mrow) * 32 + quad * 8];
            bfr[t4] = *(const bf16x8*)&Bs[ib][(wc + t4 * 16 + mrow) * 32 + quad * 8];
        }
        #pragma unroll
        for (int ti = 0; ti < 4; ++ti)
            #pragma unroll
            for (int tj = 0; tj < 4; ++tj)
                acc[ti][tj] = __builtin_amdgcn_mfma_f32_16x16x32_bf16(
                                  bfr[tj], af[ti], acc[ti][tj], 0, 0, 0);
    }

    #pragma unroll
    for (int ti = 0; ti < 4; ++ti) {
        const int row = row0 + wr + ti * 16 + mrow;
        #pragma unroll
        for (int tj = 0; tj < 4; ++tj) {
            const int col = col0 + wc + tj * 16 + quad * 4;
            const float4 bv = *(const float4*)(bias + col);
            ushort4 o;
            o.x = f2b(fmaxf(acc[ti][tj][0] + bv.x, 0.f));
            o.y = f2b(fmaxf(acc[ti][tj][1] + bv.y, 0.f));
            o.z = f2b(fmaxf(acc[ti][tj][2] + bv.z, 0.f));
            o.w = f2b(fmaxf(acc[ti][tj][3] + bv.w, 0.f));
            *(ushort4*)(Cb + (size_t)row * Nout + col) = o;
        }
    }
}

// ---------------------------------------------------------------------------
// Nout=256 GEMM (out-proj K=256, FFN2 K=1024): A bf16, W fp32.
// 128x64 tile, BK=32, single-barrier dbuf, grid 8*4*22 swizzled.
// ---------------------------------------------------------------------------
__global__ __launch_bounds__(256)
void gemm_n64(const unsigned short* __restrict__ A,
              const float* __restrict__ W, const float* __restrict__ bias,
              unsigned short* __restrict__ Cb, int K)
{
    const int id  = blockIdx.x;
    const int xcd = id & 7;
    const int j   = id >> 3;
    const int c   = j & 3;
    const int r   = 8 * (j >> 2) + xcd;
    if (r >= NROWP) return;
    const int row0 = r * 128, col0 = c * 64;

    __shared__ unsigned short As[2][128 * 32];   // 16 KB
    __shared__ unsigned short Bs[2][64 * 32];    // 8 KB
    const int tid  = threadIdx.x;
    const int lane = tid & 63;
    const int wave = tid >> 6;
    const int wr = wave * 32;
    const int mrow = lane & 15, quad = lane >> 4;

    const int ri = tid >> 1, ki = (tid & 1) * 16;   // A staging
    const int rb = tid >> 2, kb = (tid & 3) * 8;    // B staging (64x32)
    const unsigned short* Ap = A + (size_t)(row0 + ri) * K + ki;
    const float* Bp = W + (size_t)(col0 + rb) * K + kb;

    f32x4 acc[2][4] = {};
    uint4 ua0, ua1; float4 b0, b1;
    ua0 = ((const uint4*)Ap)[0]; ua1 = ((const uint4*)Ap)[1];
    b0 = ((const float4*)Bp)[0]; b1 = ((const float4*)Bp)[1];

    int ib = 0;
    for (int k0 = 0; k0 < K; k0 += 32, ib ^= 1) {
        *(uint4*)&As[ib][ri * 32 + ki]     = ua0;
        *(uint4*)&As[ib][ri * 32 + ki + 8] = ua1;
        *(uint4*)&Bs[ib][rb * 32 + kb]     = cvt8(b0, b1);
        __syncthreads();
        if (k0 + 32 < K) {
            ua0 = ((const uint4*)(Ap + k0 + 32))[0];
            ua1 = ((const uint4*)(Ap + k0 + 32))[1];
            b0 = ((const float4*)(Bp + k0 + 32))[0];
            b1 = ((const float4*)(Bp + k0 + 32))[1];
        }
        bf16x8 af[2], bfr[4];
        #pragma unroll
        for (int ti = 0; ti < 2; ++ti)
            af[ti] = *(const bf16x8*)&As[ib][(wr + ti * 16 + mrow) * 32 + quad * 8];
        #pragma unroll
        for (int tj = 0; tj < 4; ++tj)
            bfr[tj] = *(const bf16x8*)&Bs[ib][(tj * 16 + mrow) * 32 + quad * 8];
        #pragma unroll
        for (int ti = 0; ti < 2; ++ti)
            #pragma unroll
            for (int tj = 0; tj < 4; ++tj)
                acc[ti][tj] = __builtin_amdgcn_mfma_f32_16x16x32_bf16(
                                  bfr[tj], af[ti], acc[ti][tj], 0, 0, 0);
    }

    #pragma unroll
    for (int ti = 0; ti < 2; ++ti) {
        const int row = row0 + wr + ti * 16 + mrow;
        #pragma unroll
        for (int tj = 0; tj < 4; ++tj) {
            const int col = col0 + tj * 16 + quad * 4;
            const float4 bv = *(const float4*)(bias + col);
            ushort4 o;
            o.x = f2b(acc[ti][tj][0] + bv.x);
            o.y = f2b(acc[ti][tj][1] + bv.y);
            o.z = f2b(acc[ti][tj][2] + bv.z);
            o.w = f2b(acc[ti][tj][3] + bv.w);
            *(ushort4*)(Cb + (size_t)row * 256 + col) = o;
        }
    }
}

// ---------------------------------------------------------------------------
// Fused add + LayerNorm (D=256), one wave per row, 4 rows/block.
// ---------------------------------------------------------------------------
__global__ __launch_bounds__(256)
void addln_kernel(const unsigned short* __restrict__ c,
                  const float* __restrict__ resid_f,
                  const unsigned short* __restrict__ resid_b,
                  const float* __restrict__ g, const float* __restrict__ be,
                  float* __restrict__ out_f, unsigned short* __restrict__ out_b)
{
    const int wave = threadIdx.x >> 6;
    const int lane = threadIdx.x & 63;
    const int row  = blockIdx.x * 4 + wave;
    const size_t base = (size_t)row * 256 + (lane << 2);

    const ushort4 cu = *(const ushort4*)(c + base);
    float4 v;
    v.x = b2f(cu.x); v.y = b2f(cu.y); v.z = b2f(cu.z); v.w = b2f(cu.w);
    if (resid_f) {
        const float4 r = *(const float4*)(resid_f + base);
        v.x += r.x; v.y += r.y; v.z += r.z; v.w += r.w;
    } else {
        const ushort4 r = *(const ushort4*)(resid_b + base);
        v.x += b2f(r.x); v.y += b2f(r.y); v.z += b2f(r.z); v.w += b2f(r.w);
    }

    float s  = v.x + v.y + v.z + v.w;
    float ss = v.x * v.x + v.y * v.y + v.z * v.z + v.w * v.w;
    #pragma unroll
    for (int off = 32; off; off >>= 1) {
        s  += __shfl_xor(s, off, 64);
        ss += __shfl_xor(ss, off, 64);
    }
    const float mean = s * (1.f / 256.f);
    const float var  = ss * (1.f / 256.f) - mean * mean;
    const float rstd = rsqrtf(var + 1e-5f);

    const float4 gv = *(const float4*)(g  + (lane << 2));
    const float4 bv = *(const float4*)(be + (lane << 2));
    float4 o;
    o.x = (v.x - mean) * rstd * gv.x + bv.x;
    o.y = (v.y - mean) * rstd * gv.y + bv.y;
    o.z = (v.z - mean) * rstd * gv.z + bv.z;
    o.w = (v.w - mean) * rstd * gv.w + bv.w;
    if (out_f) *(float4*)(out_f + base) = o;
    if (out_b) {
        ushort4 u; u.x = f2b(o.x); u.y = f2b(o.y); u.z = f2b(o.z); u.w = f2b(o.w);
        *(ushort4*)(out_b + base) = u;
    }
}

// ---------------------------------------------------------------------------
// Deformable sampling. 256 threads, 8 tokens/block. Phase B: batched 8-deep
// gathers (8 outstanding uint4 loads per thread) for MLP.
// ---------------------------------------------------------------------------
__global__ __launch_bounds__(256)
void sampling_kernel(const unsigned short* __restrict__ value,
                     const unsigned short* __restrict__ oa,
                     const float* __restrict__ refp,
                     unsigned short* __restrict__ samp)
{
    __shared__ unsigned s_pk[64 * 68];   // 17.4 KB
    const int t0  = blockIdx.x * 8;
    const int tid = threadIdx.x;

    #pragma unroll
    for (int rep = 0; rep < 4; ++rep) {
        const int e   = rep * 256 + tid;      // 0..1023
        const int tok = e >> 7;
        const int hp  = e & 127;
        const int h   = hp >> 4, i16 = hp & 15, l = i16 >> 2;
        const int t   = t0 + tok;

        const float ex = __expf(b2f(oa[(size_t)t * 384 + 256 + h * 16 + i16]));
        float ssum = ex;
        #pragma unroll
        for (int o = 8; o; o >>= 1) ssum += __shfl_xor(ssum, o, 16);
        const float aw = ex / ssum;

        const int   Wl_t[4]  = {64, 32, 16, 8};
        const int   LST_t[4] = {0, 4096, 5120, 5376};
        const int   Wl  = Wl_t[l];
        const int   LST = LST_t[l];
        const float fW  = (float)Wl;

        const unsigned ov = *(const unsigned*)&oa[(size_t)t * 384 + h * 32 + i16 * 2];
        const float ox = lo_bf(ov), oy = hi_bf(ov);
        const float2 rxy = *(const float2*)&refp[(size_t)t * 8 + l * 2];
        const float x = rxy.x * fW + ox - 0.5f;
        const float y = rxy.y * fW + oy - 0.5f;
        const float x0 = floorf(x), y0 = floorf(y);
        const float fx = x - x0, fy = y - y0;
        const int   ix = (int)x0, iy = (int)y0;
        const bool  vx0 = (ix >= 0) & (ix < Wl), vx1 = (ix + 1 >= 0) & (ix + 1 < Wl);

        const int base = (tok * 8 + h) * 68 + i16 * 4;
        #pragma unroll
        for (int jj = 0; jj < 2; ++jj) {
            const int  yv = iy + jj;
            const bool vy = (yv >= 0) & (yv < Wl);
            const float wy = (jj ? fy : 1.f - fy) * aw;
            const int  rowi = LST + yv * Wl;
            const float w0 = (vy & vx0) ? wy * (1.f - fx) : 0.f;
            const float w1 = (vy & vx1) ? wy * fx : 0.f;
            const unsigned i0 = (vy & vx0) ? (unsigned)(rowi + ix) : 0u;
            const unsigned i1 = (vy & vx1) ? (unsigned)(rowi + ix + 1) : 0u;
            s_pk[base + jj * 2 + 0] = (i0 << 16) | f2b(w0);
            s_pk[base + jj * 2 + 1] = (i1 << 16) | f2b(w1);
        }
    }
    __syncthreads();

    const int wv_  = tid >> 6;
    const int lane = tid & 63;
    const int t2   = lane >> 5;
    const int h    = (lane >> 2) & 7;
    const int dq   = lane & 3;
    const int tok  = wv_ * 2 + t2;
    const int t    = t0 + tok;
    const int b    = t / NTOK;
    const char* vb = (const char*)value + ((size_t)b * NTOK * 256 + h * 32 + dq * 8) * 2;
    const unsigned* sp = s_pk + (tok * 8 + h) * 68;

    float a0 = 0.f, a1 = 0.f, a2 = 0.f, a3 = 0.f;
    float a4 = 0.f, a5 = 0.f, a6 = 0.f, a7 = 0.f;

    #pragma unroll
    for (int g = 0; g < 8; ++g) {
        unsigned pk[8];
        #pragma unroll
        for (int jj = 0; jj < 8; ++jj) pk[jj] = sp[g * 8 + jj];
        uint4 vv[8];
        #pragma unroll
        for (int jj = 0; jj < 8; ++jj)
            vv[jj] = *(const uint4*)(vb + (size_t)(pk[jj] >> 16) * 512);
        #pragma unroll
        for (int jj = 0; jj < 8; ++jj) {
            const float w = lo_bf(pk[jj]);
            a0 += lo_bf(vv[jj].x) * w; a1 += hi_bf(vv[jj].x) * w;
            a2 += lo_bf(vv[jj].y) * w; a3 += hi_bf(vv[jj].y) * w;
            a4 += lo_bf(vv[jj].z) * w; a5 += hi_bf(vv[jj].z) * w;
            a6 += lo_bf(vv[jj].w) * w; a7 += hi_bf(vv[jj].w) * w;
        }
    }
    ushort4 o0, o1;
    o0.x = f2b(a0); o0.y = f2b(a1); o0.z = f2b(a2); o0.w = f2b(a3);
    o1.x = f2b(a4); o1.y = f2b(a5); o1.z = f2b(a6); o1.w = f2b(a7);
    unsigned short* op = samp + (size_t)t * 256 + h * 32 + dq * 8;
    *(ushort4*)(op)     = o0;
    *(ushort4*)(op + 4) = o1;
}

// ---------------------------------------------------------------------------
extern "C" void kernel_launch(void* const* d_in, const int* in_sizes, int n_in,
                              void* d_out, int out_size, void* d_ws, size_t ws_size,
                              hipStream_t stream) {
    const float* src     = (const float*)d_in[0];
    const float* pos     = (const float*)d_in[1];
    const float* refp    = (const float*)d_in[2];
    const float* w_value = (const float*)d_in[3];
    const float* b_value = (const float*)d_in[4];
    const float* w_off   = (const float*)d_in[5];
    const float* b_off   = (const float*)d_in[6];
    const float* w_attn  = (const float*)d_in[7];
    const float* b_attn  = (const float*)d_in[8];
    const float* w_out   = (const float*)d_in[9];
    const float* b_out   = (const float*)d_in[10];
    const float* g1      = (const float*)d_in[11];
    const float* be1     = (const float*)d_in[12];
    const float* w1      = (const float*)d_in[13];
    const float* b1      = (const float*)d_in[14];
    const float* w2      = (const float*)d_in[15];
    const float* b2      = (const float*)d_in[16];
    const float* g2      = (const float*)d_in[17];
    const float* be2     = (const float*)d_in[18];
    const unsigned char* pmask = (const unsigned char*)d_in[21];

    // ---- workspace (~84 MB) ----
    char* ws = (char*)d_ws;
    const size_t SZ16  = (size_t)MTOT * 256 * 2;   // 11,141,120 B
    const size_t SZ384 = (size_t)MTOT * 384 * 2;   // 16,711,680 B
    unsigned short* value_b = (unsigned short*)(ws);
    unsigned short* oa_b    = (unsigned short*)(ws + SZ16);
    unsigned short* samp    = (unsigned short*)(ws + SZ16 + SZ384);
    unsigned short* h_bf    = (unsigned short*)(ws + 2 * SZ16 + SZ384);
    // aliases (lifetimes disjoint):
    unsigned short* C1_bf   = value_b;   // after sampling consumed value
    unsigned short* x_bf    = oa_b;      // after sampling consumed oa
    unsigned short* C2_bf   = samp;      // after out-proj consumed samp

    const dim3 blk(256);

    // value / [off|attn]  (fused fp32->bf16 conversion, pipelined K-loop)
    qkv_gemm<<<dim3(8 * 5 * 22), blk, 0, stream>>>(
        src, pos, w_value, w_off, w_attn, b_value, b_off, b_attn, pmask,
        value_b, oa_b);
    // deformable sampling -> bf16
    sampling_kernel<<<dim3(MTOT / 8), blk, 0, stream>>>(value_b, oa_b, refp, samp);
    // C1 = samp @ w_out^T + b_out
    gemm_n64<<<dim3(8 * 4 * 22), blk, 0, stream>>>(samp, w_out, b_out, C1_bf, DMODEL);
    // x_bf = LN(src + C1)
    addln_kernel<<<dim3(MTOT / 4), blk, 0, stream>>>(
        C1_bf, src, nullptr, g1, be1, nullptr, x_bf);
    // h = relu(x @ w1^T + b1)
    ffn1_gemm<<<dim3(8 * 8 * 22), blk, 0, stream>>>(x_bf, w1, b1, h_bf);
    // C2 = h @ w2^T + b2
    gemm_n64<<<dim3(8 * 4 * 22), blk, 0, stream>>>(h_bf, w2, b2, C2_bf, FFDIM);
    // out = LN(x + C2)  (fp32)
    addln_kernel<<<dim3(MTOT / 4), blk, 0, stream>>>(
        C2_bf, nullptr, x_bf, g2, be2, (float*)d_out, nullptr);
}

// Round 9
// 270.242 us; speedup vs baseline: 1.0843x; 1.0843x over previous
//
#include <hip/hip_runtime.h>

// Problem constants
#define B_SZ   4
#define NTOK   5440
#define MTOT   (B_SZ*NTOK)   // 21760
#define DMODEL 256
#define FFDIM  1024
#define NROWP  (MTOT/128)    // 170 row panels

typedef __attribute__((ext_vector_type(8))) __bf16 bf16x8;
typedef __attribute__((ext_vector_type(4))) float  f32x4;

static __device__ __forceinline__ unsigned short f2b(float f) {
    unsigned u = __builtin_bit_cast(unsigned, f);
    u = (u + 0x7FFF + ((u >> 16) & 1)) >> 16;     // RNE (finite inputs)
    return (unsigned short)u;
}
static __device__ __forceinline__ float b2f(unsigned short s) {
    return __builtin_bit_cast(float, (unsigned)s << 16);
}
static __device__ __forceinline__ float lo_bf(unsigned u) {
    return __builtin_bit_cast(float, u << 16);
}
static __device__ __forceinline__ float hi_bf(unsigned u) {
    return __builtin_bit_cast(float, u & 0xffff0000u);
}

#define GLL(gp, lp) __builtin_amdgcn_global_load_lds( \
    (const __attribute__((address_space(1))) void*)(gp), \
    (__attribute__((address_space(3))) void*)(lp), 16, 0, 0)

// s_waitcnt imm (gfx9): vmcnt[3:0]|[15:14], expcnt[6:4], lgkmcnt[11:8]
#define WAITVM(n)  __builtin_amdgcn_s_waitcnt(0x0F70 | (n))   // vmcnt(n), others dc
#define WAITLGKM0  __builtin_amdgcn_s_waitcnt(0xC07F)          // lgkmcnt(0), others dc
#define BAR        __builtin_amdgcn_s_barrier()

// ---------------------------------------------------------------------------
// qkv GEMM, async pipelined K-loop. A bf16 (src_bf or q_bf), W bf16.
// 128x128 tile, BK=32, K=256 (8 iters), LDS dbuf; GLLs stay in flight
// across barriers (wait vmcnt(4), never 0 until the tail).
// Grid 8*5*22 swizzled (xcd = id&7).
// ---------------------------------------------------------------------------
__global__ __launch_bounds__(256)
void qkv_gemm(const unsigned short* __restrict__ src_bf,
              const unsigned short* __restrict__ q_bf,
              const unsigned short* __restrict__ wv_b,
              const unsigned short* __restrict__ woa_b,
              const float* __restrict__ b_value,
              const float* __restrict__ b_off, const float* __restrict__ b_attn,
              const unsigned char* __restrict__ rowmask,
              unsigned short* __restrict__ value_b, unsigned short* __restrict__ oa_b)
{
    const int K = 256;
    const int id  = blockIdx.x;
    const int xcd = id & 7;
    const int j   = id >> 3;
    const int c   = j % 5;
    const int r   = 8 * (j / 5) + xcd;
    if (r >= NROWP) return;
    const int row0 = r * 128;
    const bool isv = (c < 2);
    const unsigned short* A  = isv ? src_bf : q_bf;
    const unsigned short* Wt = isv ? wv_b : woa_b;
    unsigned short* C = isv ? value_b : oa_b;
    const int ldc  = isv ? 256 : 384;
    const int col0 = (isv ? c : (c - 2)) * 128;

    __shared__ unsigned short As[2][128 * 32];
    __shared__ unsigned short Bs[2][128 * 32];
    const int tid  = threadIdx.x;
    const int lane = tid & 63;
    const int wave = tid >> 6;
    const int wr = (wave >> 1) * 64, wc = (wave & 1) * 64;
    const int mrow = lane & 15, quad = lane >> 4;

    const int ri0 = tid >> 2,         ki0 = (tid & 3) * 8;
    const int ri1 = (256 + tid) >> 2, ki1 = ((256 + tid) & 3) * 8;
    const int lds0 = (wave * 64) * 8, lds1 = (256 + wave * 64) * 8;

    const unsigned short* Ar0 = A  + (size_t)(row0 + ri0) * K + ki0;
    const unsigned short* Br0 = Wt + (size_t)(col0 + ri0) * K + ki0;
    const unsigned short* Ar1 = A  + (size_t)(row0 + ri1) * K + ki1;
    const unsigned short* Br1 = Wt + (size_t)(col0 + ri1) * K + ki1;

    f32x4 acc[4][4] = {};

    // prologue: tiles 0 and 1 in flight
    GLL(Ar0 +  0, &As[0][lds0]); GLL(Br0 +  0, &Bs[0][lds0]);
    GLL(Ar1 +  0, &As[0][lds1]); GLL(Br1 +  0, &Bs[0][lds1]);
    GLL(Ar0 + 32, &As[1][lds0]); GLL(Br0 + 32, &Bs[1][lds0]);
    GLL(Ar1 + 32, &As[1][lds1]); GLL(Br1 + 32, &Bs[1][lds1]);

    #pragma unroll
    for (int k = 0; k < 8; ++k) {
        if (k < 7) WAITVM(4); else WAITVM(0);   // tile k's own loads done
        BAR;                                     // all waves staged tile k
        const int b = k & 1;
        bf16x8 af[4], bfr[4];
        #pragma unroll
        for (int t4 = 0; t4 < 4; ++t4) {
            af[t4]  = *(const bf16x8*)&As[b][(wr + t4 * 16 + mrow) * 32 + quad * 8];
            bfr[t4] = *(const bf16x8*)&Bs[b][(wc + t4 * 16 + mrow) * 32 + quad * 8];
        }
        WAITLGKM0;                               // my fragment reads landed
        BAR;                                     // everyone's reads landed
        if (k + 2 < 8) {                         // refill buffer b with tile k+2
            const int kk = (k + 2) * 32;
            GLL(Ar0 + kk, &As[b][lds0]); GLL(Br0 + kk, &Bs[b][lds0]);
            GLL(Ar1 + kk, &As[b][lds1]); GLL(Br1 + kk, &Bs[b][lds1]);
        }
        #pragma unroll
        for (int ti = 0; ti < 4; ++ti)
            #pragma unroll
            for (int tj = 0; tj < 4; ++tj)
                acc[ti][tj] = __builtin_amdgcn_mfma_f32_16x16x32_bf16(
                                  bfr[tj], af[ti], acc[ti][tj], 0, 0, 0);
    }

    // swapped D layout: row = ..+mrow, col = ..+quad*4+r ; ushort4 stores
    #pragma unroll
    for (int ti = 0; ti < 4; ++ti) {
        const int row = row0 + wr + ti * 16 + mrow;
        const bool msk = isv && rowmask[row];
        #pragma unroll
        for (int tj = 0; tj < 4; ++tj) {
            const int col = col0 + wc + tj * 16 + quad * 4;
            const float4 bv = isv ? *(const float4*)(b_value + col)
                            : (col < 256 ? *(const float4*)(b_off + col)
                                         : *(const float4*)(b_attn + col - 256));
            ushort4 o;
            o.x = msk ? 0 : f2b(acc[ti][tj][0] + bv.x);
            o.y = msk ? 0 : f2b(acc[ti][tj][1] + bv.y);
            o.z = msk ? 0 : f2b(acc[ti][tj][2] + bv.z);
            o.w = msk ? 0 : f2b(acc[ti][tj][3] + bv.w);
            *(ushort4*)(C + (size_t)row * ldc + col) = o;
        }
    }
}

// ---------------------------------------------------------------------------
// FFN1: C = relu(A @ Wt^T + bias) bf16. K=256, Nout=1024. Async pipeline.
// Grid 8*8*22 swizzled.
// ---------------------------------------------------------------------------
__global__ __launch_bounds__(256)
void ffn1_gemm(const unsigned short* __restrict__ A,
               const unsigned short* __restrict__ Wt,
               const float* __restrict__ bias,
               unsigned short* __restrict__ Cb)
{
    const int K = 256, Nout = 1024;
    const int id  = blockIdx.x;
    const int xcd = id & 7;
    const int j   = id >> 3;
    const int c   = j & 7;
    const int r   = 8 * (j >> 3) + xcd;
    if (r >= NROWP) return;
    const int row0 = r * 128, col0 = c * 128;

    __shared__ unsigned short As[2][128 * 32];
    __shared__ unsigned short Bs[2][128 * 32];
    const int tid  = threadIdx.x;
    const int lane = tid & 63;
    const int wave = tid >> 6;
    const int wr = (wave >> 1) * 64, wc = (wave & 1) * 64;
    const int mrow = lane & 15, quad = lane >> 4;

    const int ri0 = tid >> 2,         ki0 = (tid & 3) * 8;
    const int ri1 = (256 + tid) >> 2, ki1 = ((256 + tid) & 3) * 8;
    const int lds0 = (wave * 64) * 8, lds1 = (256 + wave * 64) * 8;

    const unsigned short* Ar0 = A  + (size_t)(row0 + ri0) * K + ki0;
    const unsigned short* Br0 = Wt + (size_t)(col0 + ri0) * K + ki0;
    const unsigned short* Ar1 = A  + (size_t)(row0 + ri1) * K + ki1;
    const unsigned short* Br1 = Wt + (size_t)(col0 + ri1) * K + ki1;

    f32x4 acc[4][4] = {};

    GLL(Ar0 +  0, &As[0][lds0]); GLL(Br0 +  0, &Bs[0][lds0]);
    GLL(Ar1 +  0, &As[0][lds1]); GLL(Br1 +  0, &Bs[0][lds1]);
    GLL(Ar0 + 32, &As[1][lds0]); GLL(Br0 + 32, &Bs[1][lds0]);
    GLL(Ar1 + 32, &As[1][lds1]); GLL(Br1 + 32, &Bs[1][lds1]);

    #pragma unroll
    for (int k = 0; k < 8; ++k) {
        if (k < 7) WAITVM(4); else WAITVM(0);
        BAR;
        const int b = k & 1;
        bf16x8 af[4], bfr[4];
        #pragma unroll
        for (int t4 = 0; t4 < 4; ++t4) {
            af[t4]  = *(const bf16x8*)&As[b][(wr + t4 * 16 + mrow) * 32 + quad * 8];
            bfr[t4] = *(const bf16x8*)&Bs[b][(wc + t4 * 16 + mrow) * 32 + quad * 8];
        }
        WAITLGKM0;
        BAR;
        if (k + 2 < 8) {
            const int kk = (k + 2) * 32;
            GLL(Ar0 + kk, &As[b][lds0]); GLL(Br0 + kk, &Bs[b][lds0]);
            GLL(Ar1 + kk, &As[b][lds1]); GLL(Br1 + kk, &Bs[b][lds1]);
        }
        #pragma unroll
        for (int ti = 0; ti < 4; ++ti)
            #pragma unroll
            for (int tj = 0; tj < 4; ++tj)
                acc[ti][tj] = __builtin_amdgcn_mfma_f32_16x16x32_bf16(
                                  bfr[tj], af[ti], acc[ti][tj], 0, 0, 0);
    }

    #pragma unroll
    for (int ti = 0; ti < 4; ++ti) {
        const int row = row0 + wr + ti * 16 + mrow;
        #pragma unroll
        for (int tj = 0; tj < 4; ++tj) {
            const int col = col0 + wc + tj * 16 + quad * 4;
            const float4 bv = *(const float4*)(bias + col);
            ushort4 o;
            o.x = f2b(fmaxf(acc[ti][tj][0] + bv.x, 0.f));
            o.y = f2b(fmaxf(acc[ti][tj][1] + bv.y, 0.f));
            o.z = f2b(fmaxf(acc[ti][tj][2] + bv.z, 0.f));
            o.w = f2b(fmaxf(acc[ti][tj][3] + bv.w, 0.f));
            *(ushort4*)(Cb + (size_t)row * Nout + col) = o;
        }
    }
}

// ---------------------------------------------------------------------------
// Nout=256 GEMM, 128x64 tile, async pipeline. NK = K/32 (template).
// Grid 8*4*22 swizzled. Per-iter 3 GLLs; steady in-flight 6 -> wait vmcnt(3).
// ---------------------------------------------------------------------------
template<int NK>
__global__ __launch_bounds__(256)
void gemm_n64(const unsigned short* __restrict__ A,
              const unsigned short* __restrict__ Wt,
              const float* __restrict__ bias,
              unsigned short* __restrict__ Cb)
{
    const int K = NK * 32;
    const int id  = blockIdx.x;
    const int xcd = id & 7;
    const int j   = id >> 3;
    const int c   = j & 3;
    const int r   = 8 * (j >> 2) + xcd;
    if (r >= NROWP) return;
    const int row0 = r * 128, col0 = c * 64;

    __shared__ unsigned short As[2][128 * 32];   // 16 KB
    __shared__ unsigned short Bs[2][64 * 32];    // 8 KB
    const int tid  = threadIdx.x;
    const int lane = tid & 63;
    const int wave = tid >> 6;
    const int wr = wave * 32;
    const int mrow = lane & 15, quad = lane >> 4;

    const int ri0 = tid >> 2,         ki0 = (tid & 3) * 8;
    const int ri1 = (256 + tid) >> 2, ki1 = ((256 + tid) & 3) * 8;
    const int lds0 = (wave * 64) * 8, lds1 = (256 + wave * 64) * 8;

    const unsigned short* Ar0 = A  + (size_t)(row0 + ri0) * K + ki0;
    const unsigned short* Ar1 = A  + (size_t)(row0 + ri1) * K + ki1;
    const unsigned short* Br0 = Wt + (size_t)(col0 + ri0) * K + ki0;  // rows 0..63

    f32x4 acc[2][4] = {};

    GLL(Ar0 +  0, &As[0][lds0]); GLL(Ar1 +  0, &As[0][lds1]);
    GLL(Br0 +  0, &Bs[0][lds0]);
    GLL(Ar0 + 32, &As[1][lds0]); GLL(Ar1 + 32, &As[1][lds1]);
    GLL(Br0 + 32, &Bs[1][lds0]);

    #pragma unroll
    for (int k = 0; k < NK; ++k) {
        if (k < NK - 1) WAITVM(3); else WAITVM(0);
        BAR;
        const int b = k & 1;
        bf16x8 af[2], bfr[4];
        #pragma unroll
        for (int ti = 0; ti < 2; ++ti)
            af[ti] = *(const bf16x8*)&As[b][(wr + ti * 16 + mrow) * 32 + quad * 8];
        #pragma unroll
        for (int tj = 0; tj < 4; ++tj)
            bfr[tj] = *(const bf16x8*)&Bs[b][(tj * 16 + mrow) * 32 + quad * 8];
        WAITLGKM0;
        BAR;
        if (k + 2 < NK) {
            const int kk = (k + 2) * 32;
            GLL(Ar0 + kk, &As[b][lds0]); GLL(Ar1 + kk, &As[b][lds1]);
            GLL(Br0 + kk, &Bs[b][lds0]);
        }
        #pragma unroll
        for (int ti = 0; ti < 2; ++ti)
            #pragma unroll
            for (int tj = 0; tj < 4; ++tj)
                acc[ti][tj] = __builtin_amdgcn_mfma_f32_16x16x32_bf16(
                                  bfr[tj], af[ti], acc[ti][tj], 0, 0, 0);
    }

    #pragma unroll
    for (int ti = 0; ti < 2; ++ti) {
        const int row = row0 + wr + ti * 16 + mrow;
        #pragma unroll
        for (int tj = 0; tj < 4; ++tj) {
            const int col = col0 + tj * 16 + quad * 4;
            const float4 bv = *(const float4*)(bias + col);
            ushort4 o;
            o.x = f2b(acc[ti][tj][0] + bv.x);
            o.y = f2b(acc[ti][tj][1] + bv.y);
            o.z = f2b(acc[ti][tj][2] + bv.z);
            o.w = f2b(acc[ti][tj][3] + bv.w);
            *(ushort4*)(Cb + (size_t)row * 256 + col) = o;
        }
    }
}

// ---------------------------------------------------------------------------
// Fused add + LayerNorm (D=256), one wave per row, 4 rows/block.
// ---------------------------------------------------------------------------
__global__ __launch_bounds__(256)
void addln_kernel(const unsigned short* __restrict__ c,
                  const float* __restrict__ resid_f,
                  const unsigned short* __restrict__ resid_b,
                  const float* __restrict__ g, const float* __restrict__ be,
                  float* __restrict__ out_f, unsigned short* __restrict__ out_b)
{
    const int wave = threadIdx.x >> 6;
    const int lane = threadIdx.x & 63;
    const int row  = blockIdx.x * 4 + wave;
    const size_t base = (size_t)row * 256 + (lane << 2);

    const ushort4 cu = *(const ushort4*)(c + base);
    float4 v;
    v.x = b2f(cu.x); v.y = b2f(cu.y); v.z = b2f(cu.z); v.w = b2f(cu.w);
    if (resid_f) {
        const float4 r = *(const float4*)(resid_f + base);
        v.x += r.x; v.y += r.y; v.z += r.z; v.w += r.w;
    } else {
        const ushort4 r = *(const ushort4*)(resid_b + base);
        v.x += b2f(r.x); v.y += b2f(r.y); v.z += b2f(r.z); v.w += b2f(r.w);
    }

    float s  = v.x + v.y + v.z + v.w;
    float ss = v.x * v.x + v.y * v.y + v.z * v.z + v.w * v.w;
    #pragma unroll
    for (int off = 32; off; off >>= 1) {
        s  += __shfl_xor(s, off, 64);
        ss += __shfl_xor(ss, off, 64);
    }
    const float mean = s * (1.f / 256.f);
    const float var  = ss * (1.f / 256.f) - mean * mean;
    const float rstd = rsqrtf(var + 1e-5f);

    const float4 gv = *(const float4*)(g  + (lane << 2));
    const float4 bv = *(const float4*)(be + (lane << 2));
    float4 o;
    o.x = (v.x - mean) * rstd * gv.x + bv.x;
    o.y = (v.y - mean) * rstd * gv.y + bv.y;
    o.z = (v.z - mean) * rstd * gv.z + bv.z;
    o.w = (v.w - mean) * rstd * gv.w + bv.w;
    if (out_f) *(float4*)(out_f + base) = o;
    if (out_b) {
        ushort4 u; u.x = f2b(o.x); u.y = f2b(o.y); u.z = f2b(o.z); u.w = f2b(o.w);
        *(ushort4*)(out_b + base) = u;
    }
}

// ---------------------------------------------------------------------------
// Deformable sampling. 256 threads, 8 tokens/block; batched 8-deep gathers.
// ---------------------------------------------------------------------------
__global__ __launch_bounds__(256)
void sampling_kernel(const unsigned short* __restrict__ value,
                     const unsigned short* __restrict__ oa,
                     const float* __restrict__ refp,
                     unsigned short* __restrict__ samp)
{
    __shared__ unsigned s_pk[64 * 68];   // 17.4 KB
    const int t0  = blockIdx.x * 8;
    const int tid = threadIdx.x;

    #pragma unroll
    for (int rep = 0; rep < 4; ++rep) {
        const int e   = rep * 256 + tid;      // 0..1023
        const int tok = e >> 7;
        const int hp  = e & 127;
        const int h   = hp >> 4, i16 = hp & 15, l = i16 >> 2;
        const int t   = t0 + tok;

        const float ex = __expf(b2f(oa[(size_t)t * 384 + 256 + h * 16 + i16]));
        float ssum = ex;
        #pragma unroll
        for (int o = 8; o; o >>= 1) ssum += __shfl_xor(ssum, o, 16);
        const float aw = ex / ssum;

        const int   Wl_t[4]  = {64, 32, 16, 8};
        const int   LST_t[4] = {0, 4096, 5120, 5376};
        const int   Wl  = Wl_t[l];
        const int   LST = LST_t[l];
        const float fW  = (float)Wl;

        const unsigned ov = *(const unsigned*)&oa[(size_t)t * 384 + h * 32 + i16 * 2];
        const float ox = lo_bf(ov), oy = hi_bf(ov);
        const float2 rxy = *(const float2*)&refp[(size_t)t * 8 + l * 2];
        const float x = rxy.x * fW + ox - 0.5f;
        const float y = rxy.y * fW + oy - 0.5f;
        const float x0 = floorf(x), y0 = floorf(y);
        const float fx = x - x0, fy = y - y0;
        const int   ix = (int)x0, iy = (int)y0;
        const bool  vx0 = (ix >= 0) & (ix < Wl), vx1 = (ix + 1 >= 0) & (ix + 1 < Wl);

        const int base = (tok * 8 + h) * 68 + i16 * 4;
        #pragma unroll
        for (int jj = 0; jj < 2; ++jj) {
            const int  yv = iy + jj;
            const bool vy = (yv >= 0) & (yv < Wl);
            const float wy = (jj ? fy : 1.f - fy) * aw;
            const int  rowi = LST + yv * Wl;
            const float w0 = (vy & vx0) ? wy * (1.f - fx) : 0.f;
            const float w1 = (vy & vx1) ? wy * fx : 0.f;
            const unsigned i0 = (vy & vx0) ? (unsigned)(rowi + ix) : 0u;
            const unsigned i1 = (vy & vx1) ? (unsigned)(rowi + ix + 1) : 0u;
            s_pk[base + jj * 2 + 0] = (i0 << 16) | f2b(w0);
            s_pk[base + jj * 2 + 1] = (i1 << 16) | f2b(w1);
        }
    }
    __syncthreads();

    const int wv_  = tid >> 6;
    const int lane = tid & 63;
    const int t2   = lane >> 5;
    const int h    = (lane >> 2) & 7;
    const int dq   = lane & 3;
    const int tok  = wv_ * 2 + t2;
    const int t    = t0 + tok;
    const int b    = t / NTOK;
    const char* vb = (const char*)value + ((size_t)b * NTOK * 256 + h * 32 + dq * 8) * 2;
    const unsigned* sp = s_pk + (tok * 8 + h) * 68;

    float a0 = 0.f, a1 = 0.f, a2 = 0.f, a3 = 0.f;
    float a4 = 0.f, a5 = 0.f, a6 = 0.f, a7 = 0.f;

    #pragma unroll
    for (int g = 0; g < 8; ++g) {
        unsigned pk[8];
        #pragma unroll
        for (int jj = 0; jj < 8; ++jj) pk[jj] = sp[g * 8 + jj];
        uint4 vv[8];
        #pragma unroll
        for (int jj = 0; jj < 8; ++jj)
            vv[jj] = *(const uint4*)(vb + (size_t)(pk[jj] >> 16) * 512);
        #pragma unroll
        for (int jj = 0; jj < 8; ++jj) {
            const float w = lo_bf(pk[jj]);
            a0 += lo_bf(vv[jj].x) * w; a1 += hi_bf(vv[jj].x) * w;
            a2 += lo_bf(vv[jj].y) * w; a3 += hi_bf(vv[jj].y) * w;
            a4 += lo_bf(vv[jj].z) * w; a5 += hi_bf(vv[jj].z) * w;
            a6 += lo_bf(vv[jj].w) * w; a7 += hi_bf(vv[jj].w) * w;
        }
    }
    ushort4 o0, o1;
    o0.x = f2b(a0); o0.y = f2b(a1); o0.z = f2b(a2); o0.w = f2b(a3);
    o1.x = f2b(a4); o1.y = f2b(a5); o1.z = f2b(a6); o1.w = f2b(a7);
    unsigned short* op = samp + (size_t)t * 256 + h * 32 + dq * 8;
    *(ushort4*)(op)     = o0;
    *(ushort4*)(op + 4) = o1;
}

// ---------------------------------------------------------------------------
// Prep: q_bf = bf16(src+pos), src_bf = bf16(src), plus all 6 weight cvts.
// ---------------------------------------------------------------------------
__global__ __launch_bounds__(256)
void prep_kernel(const float* __restrict__ src, const float* __restrict__ pos,
                 const float* __restrict__ wv, const float* __restrict__ woff,
                 const float* __restrict__ wattn, const float* __restrict__ wout,
                 const float* __restrict__ w1, const float* __restrict__ w2,
                 unsigned short* __restrict__ q_bf, unsigned short* __restrict__ src_bf,
                 unsigned short* __restrict__ wv_b, unsigned short* __restrict__ woa_b,
                 unsigned short* __restrict__ wout_b,
                 unsigned short* __restrict__ w1_b, unsigned short* __restrict__ w2_b)
{
    const int v = blockIdx.x * 256 + threadIdx.x;
    if (v < 1392640) {
        const float4 s = ((const float4*)src)[v];
        const float4 p = ((const float4*)pos)[v];
        ushort4 qo, so;
        qo.x = f2b(s.x + p.x); qo.y = f2b(s.y + p.y);
        qo.z = f2b(s.z + p.z); qo.w = f2b(s.w + p.w);
        so.x = f2b(s.x); so.y = f2b(s.y); so.z = f2b(s.z); so.w = f2b(s.w);
        ((ushort4*)q_bf)[v]   = qo;
        ((ushort4*)src_bf)[v] = so;
        return;
    }
    const int v2 = v - 1392640;
    const float* s; unsigned short* d; int off;
    if      (v2 <  16384) { s = wv;    d = wv_b;          off = v2; }
    else if (v2 <  32768) { s = woff;  d = woa_b;         off = v2 - 16384; }
    else if (v2 <  40960) { s = wattn; d = woa_b + 65536; off = v2 - 32768; }
    else if (v2 <  57344) { s = wout;  d = wout_b;        off = v2 - 40960; }
    else if (v2 < 122880) { s = w1;    d = w1_b;          off = v2 - 57344; }
    else                  { s = w2;    d = w2_b;          off = v2 - 122880; }
    const float4 f = ((const float4*)s)[off];
    ushort4 u; u.x = f2b(f.x); u.y = f2b(f.y); u.z = f2b(f.z); u.w = f2b(f.w);
    ((ushort4*)d)[off] = u;
}

// ---------------------------------------------------------------------------
extern "C" void kernel_launch(void* const* d_in, const int* in_sizes, int n_in,
                              void* d_out, int out_size, void* d_ws, size_t ws_size,
                              hipStream_t stream) {
    const float* src     = (const float*)d_in[0];
    const float* pos     = (const float*)d_in[1];
    const float* refp    = (const float*)d_in[2];
    const float* w_value = (const float*)d_in[3];
    const float* b_value = (const float*)d_in[4];
    const float* w_off   = (const float*)d_in[5];
    const float* b_off   = (const float*)d_in[6];
    const float* w_attn  = (const float*)d_in[7];
    const float* b_attn  = (const float*)d_in[8];
    const float* w_out   = (const float*)d_in[9];
    const float* b_out   = (const float*)d_in[10];
    const float* g1      = (const float*)d_in[11];
    const float* be1     = (const float*)d_in[12];
    const float* w1      = (const float*)d_in[13];
    const float* b1      = (const float*)d_in[14];
    const float* w2      = (const float*)d_in[15];
    const float* b2      = (const float*)d_in[16];
    const float* g2      = (const float*)d_in[17];
    const float* be2     = (const float*)d_in[18];
    const unsigned char* pmask = (const unsigned char*)d_in[21];

    // ---- workspace (~80 MB) ----
    char* ws = (char*)d_ws;
    const size_t SZ16 = (size_t)MTOT * 256 * 2;            // 11,141,120 B
    unsigned short* q_bf    = (unsigned short*)(ws);                    // [0, 11.1M)
    unsigned short* src_bf  = (unsigned short*)(ws + SZ16);             // [11.1, 22.3)
    unsigned short* value_b = (unsigned short*)(ws + 2 * SZ16);         // [22.3, 33.4)
    unsigned short* oa_b    = (unsigned short*)(ws + 3 * SZ16);         // [33.4, 50.1) MTOT*384
    unsigned short* samp    = (unsigned short*)(ws + 50135040ULL);      // [50.1, 61.3)
    unsigned short* h_bf    = (unsigned short*)(ws + 3 * SZ16);         // [33.4, 78.0) over oa+samp
    unsigned short* wts     = (unsigned short*)(ws + 77987840ULL);      // 1.6 MB
    // aliases (lifetimes disjoint):
    unsigned short* x_bf    = q_bf;      // q dead after qkv
    unsigned short* C1_bf   = value_b;   // value dead after sampling
    unsigned short* C2_bf   = src_bf;    // src_bf dead after qkv

    unsigned short* wv_b    = wts;
    unsigned short* woa_b   = wv_b   + 65536;
    unsigned short* wout_b  = woa_b  + 98304;
    unsigned short* w1_b    = wout_b + 65536;
    unsigned short* w2_b    = w1_b   + 262144;

    const dim3 blk(256);

    prep_kernel<<<dim3(6176), blk, 0, stream>>>(src, pos, w_value, w_off, w_attn,
                                                w_out, w1, w2, q_bf, src_bf,
                                                wv_b, woa_b, wout_b, w1_b, w2_b);
    // value / [off|attn]
    qkv_gemm<<<dim3(8 * 5 * 22), blk, 0, stream>>>(
        src_bf, q_bf, wv_b, woa_b, b_value, b_off, b_attn, pmask, value_b, oa_b);
    // deformable sampling -> bf16
    sampling_kernel<<<dim3(MTOT / 8), blk, 0, stream>>>(value_b, oa_b, refp, samp);
    // C1 = samp @ w_out^T + b_out
    gemm_n64<8><<<dim3(8 * 4 * 22), blk, 0, stream>>>(samp, wout_b, b_out, C1_bf);
    // x_bf = LN(src + C1)
    addln_kernel<<<dim3(MTOT / 4), blk, 0, stream>>>(
        C1_bf, src, nullptr, g1, be1, nullptr, x_bf);
    // h = relu(x @ w1^T + b1)
    ffn1_gemm<<<dim3(8 * 8 * 22), blk, 0, stream>>>(x_bf, w1_b, b1, h_bf);
    // C2 = h @ w2^T + b2
    gemm_n64<32><<<dim3(8 * 4 * 22), blk, 0, stream>>>(h_bf, w2_b, b2, C2_bf);
    // out = LN(x + C2)  (fp32)
    addln_kernel<<<dim3(MTOT / 4), blk, 0, stream>>>(
        C2_bf, nullptr, x_bf, g2, be2, (float*)d_out, nullptr);
}

// Round 10
// 269.565 us; speedup vs baseline: 1.0870x; 1.0025x over previous
//
#include <hip/hip_runtime.h>

// Problem constants
#define B_SZ   4
#define NTOK   5440
#define MTOT   (B_SZ*NTOK)   // 21760
#define DMODEL 256
#define FFDIM  1024
#define NROWP  (MTOT/128)    // 170 row panels

typedef __attribute__((ext_vector_type(8))) __bf16 bf16x8;
typedef __attribute__((ext_vector_type(4))) float  f32x4;

static __device__ __forceinline__ unsigned short f2b(float f) {
    unsigned u = __builtin_bit_cast(unsigned, f);
    u = (u + 0x7FFF + ((u >> 16) & 1)) >> 16;     // RNE (finite inputs)
    return (unsigned short)u;
}
static __device__ __forceinline__ float b2f(unsigned short s) {
    return __builtin_bit_cast(float, (unsigned)s << 16);
}
static __device__ __forceinline__ float lo_bf(unsigned u) {
    return __builtin_bit_cast(float, u << 16);
}
static __device__ __forceinline__ float hi_bf(unsigned u) {
    return __builtin_bit_cast(float, u & 0xffff0000u);
}

#define GLL(gp, lp) __builtin_amdgcn_global_load_lds( \
    (const __attribute__((address_space(1))) void*)(gp), \
    (__attribute__((address_space(3))) void*)(lp), 16, 0, 0)

// s_waitcnt imm (gfx9): vmcnt[3:0]|[15:14], expcnt[6:4], lgkmcnt[11:8]
#define WAITVM(n)  __builtin_amdgcn_s_waitcnt(0x0F70 | (n))   // vmcnt(n), others dc
#define WAITLGKM0  __builtin_amdgcn_s_waitcnt(0xC07F)          // lgkmcnt(0), others dc
#define BAR        __builtin_amdgcn_s_barrier()

// ---------------------------------------------------------------------------
// qkv GEMM, async pipelined K-loop. A bf16 (src_bf or q_bf), W bf16.
// 128x128 tile, BK=32, K=256 (8 iters), LDS dbuf; GLLs stay in flight
// across barriers (wait vmcnt(4), never 0 until the tail).
// Grid 8*5*22 swizzled (xcd = id&7).
// ---------------------------------------------------------------------------
__global__ __launch_bounds__(256)
void qkv_gemm(const unsigned short* __restrict__ src_bf,
              const unsigned short* __restrict__ q_bf,
              const unsigned short* __restrict__ wv_b,
              const unsigned short* __restrict__ woa_b,
              const float* __restrict__ b_value,
              const float* __restrict__ b_off, const float* __restrict__ b_attn,
              const unsigned char* __restrict__ rowmask,
              unsigned short* __restrict__ value_b, unsigned short* __restrict__ oa_b)
{
    const int K = 256;
    const int id  = blockIdx.x;
    const int xcd = id & 7;
    const int j   = id >> 3;
    const int c   = j % 5;
    const int r   = 8 * (j / 5) + xcd;
    if (r >= NROWP) return;
    const int row0 = r * 128;
    const bool isv = (c < 2);
    const unsigned short* A  = isv ? src_bf : q_bf;
    const unsigned short* Wt = isv ? wv_b : woa_b;
    unsigned short* C = isv ? value_b : oa_b;
    const int ldc  = isv ? 256 : 384;
    const int col0 = (isv ? c : (c - 2)) * 128;

    __shared__ unsigned short As[2][128 * 32];
    __shared__ unsigned short Bs[2][128 * 32];
    const int tid  = threadIdx.x;
    const int lane = tid & 63;
    const int wave = tid >> 6;
    const int wr = (wave >> 1) * 64, wc = (wave & 1) * 64;
    const int mrow = lane & 15, quad = lane >> 4;

    const int ri0 = tid >> 2,         ki0 = (tid & 3) * 8;
    const int ri1 = (256 + tid) >> 2, ki1 = ((256 + tid) & 3) * 8;
    const int lds0 = (wave * 64) * 8, lds1 = (256 + wave * 64) * 8;

    const unsigned short* Ar0 = A  + (size_t)(row0 + ri0) * K + ki0;
    const unsigned short* Br0 = Wt + (size_t)(col0 + ri0) * K + ki0;
    const unsigned short* Ar1 = A  + (size_t)(row0 + ri1) * K + ki1;
    const unsigned short* Br1 = Wt + (size_t)(col0 + ri1) * K + ki1;

    f32x4 acc[4][4] = {};

    // prologue: tiles 0 and 1 in flight
    GLL(Ar0 +  0, &As[0][lds0]); GLL(Br0 +  0, &Bs[0][lds0]);
    GLL(Ar1 +  0, &As[0][lds1]); GLL(Br1 +  0, &Bs[0][lds1]);
    GLL(Ar0 + 32, &As[1][lds0]); GLL(Br0 + 32, &Bs[1][lds0]);
    GLL(Ar1 + 32, &As[1][lds1]); GLL(Br1 + 32, &Bs[1][lds1]);

    #pragma unroll
    for (int k = 0; k < 8; ++k) {
        if (k < 7) WAITVM(4); else WAITVM(0);   // tile k's own loads done
        BAR;                                     // all waves staged tile k
        const int b = k & 1;
        bf16x8 af[4], bfr[4];
        #pragma unroll
        for (int t4 = 0; t4 < 4; ++t4) {
            af[t4]  = *(const bf16x8*)&As[b][(wr + t4 * 16 + mrow) * 32 + quad * 8];
            bfr[t4] = *(const bf16x8*)&Bs[b][(wc + t4 * 16 + mrow) * 32 + quad * 8];
        }
        WAITLGKM0;                               // my fragment reads landed
        BAR;                                     // everyone's reads landed
        if (k + 2 < 8) {                         // refill buffer b with tile k+2
            const int kk = (k + 2) * 32;
            GLL(Ar0 + kk, &As[b][lds0]); GLL(Br0 + kk, &Bs[b][lds0]);
            GLL(Ar1 + kk, &As[b][lds1]); GLL(Br1 + kk, &Bs[b][lds1]);
        }
        #pragma unroll
        for (int ti = 0; ti < 4; ++ti)
            #pragma unroll
            for (int tj = 0; tj < 4; ++tj)
                acc[ti][tj] = __builtin_amdgcn_mfma_f32_16x16x32_bf16(
                                  bfr[tj], af[ti], acc[ti][tj], 0, 0, 0);
    }

    // swapped D layout: row = ..+mrow, col = ..+quad*4+r ; ushort4 stores
    #pragma unroll
    for (int ti = 0; ti < 4; ++ti) {
        const int row = row0 + wr + ti * 16 + mrow;
        const bool msk = isv && rowmask[row];
        #pragma unroll
        for (int tj = 0; tj < 4; ++tj) {
            const int col = col0 + wc + tj * 16 + quad * 4;
            const float4 bv = isv ? *(const float4*)(b_value + col)
                            : (col < 256 ? *(const float4*)(b_off + col)
                                         : *(const float4*)(b_attn + col - 256));
            ushort4 o;
            o.x = msk ? 0 : f2b(acc[ti][tj][0] + bv.x);
            o.y = msk ? 0 : f2b(acc[ti][tj][1] + bv.y);
            o.z = msk ? 0 : f2b(acc[ti][tj][2] + bv.z);
            o.w = msk ? 0 : f2b(acc[ti][tj][3] + bv.w);
            *(ushort4*)(C + (size_t)row * ldc + col) = o;
        }
    }
}

// ---------------------------------------------------------------------------
// FFN1: C = relu(A @ Wt^T + bias) bf16. K=256, Nout=1024. Async pipeline.
// Grid 8*8*22 swizzled.
// ---------------------------------------------------------------------------
__global__ __launch_bounds__(256)
void ffn1_gemm(const unsigned short* __restrict__ A,
               const unsigned short* __restrict__ Wt,
               const float* __restrict__ bias,
               unsigned short* __restrict__ Cb)
{
    const int K = 256, Nout = 1024;
    const int id  = blockIdx.x;
    const int xcd = id & 7;
    const int j   = id >> 3;
    const int c   = j & 7;
    const int r   = 8 * (j >> 3) + xcd;
    if (r >= NROWP) return;
    const int row0 = r * 128, col0 = c * 128;

    __shared__ unsigned short As[2][128 * 32];
    __shared__ unsigned short Bs[2][128 * 32];
    const int tid  = threadIdx.x;
    const int lane = tid & 63;
    const int wave = tid >> 6;
    const int wr = (wave >> 1) * 64, wc = (wave & 1) * 64;
    const int mrow = lane & 15, quad = lane >> 4;

    const int ri0 = tid >> 2,         ki0 = (tid & 3) * 8;
    const int ri1 = (256 + tid) >> 2, ki1 = ((256 + tid) & 3) * 8;
    const int lds0 = (wave * 64) * 8, lds1 = (256 + wave * 64) * 8;

    const unsigned short* Ar0 = A  + (size_t)(row0 + ri0) * K + ki0;
    const unsigned short* Br0 = Wt + (size_t)(col0 + ri0) * K + ki0;
    const unsigned short* Ar1 = A  + (size_t)(row0 + ri1) * K + ki1;
    const unsigned short* Br1 = Wt + (size_t)(col0 + ri1) * K + ki1;

    f32x4 acc[4][4] = {};

    GLL(Ar0 +  0, &As[0][lds0]); GLL(Br0 +  0, &Bs[0][lds0]);
    GLL(Ar1 +  0, &As[0][lds1]); GLL(Br1 +  0, &Bs[0][lds1]);
    GLL(Ar0 + 32, &As[1][lds0]); GLL(Br0 + 32, &Bs[1][lds0]);
    GLL(Ar1 + 32, &As[1][lds1]); GLL(Br1 + 32, &Bs[1][lds1]);

    #pragma unroll
    for (int k = 0; k < 8; ++k) {
        if (k < 7) WAITVM(4); else WAITVM(0);
        BAR;
        const int b = k & 1;
        bf16x8 af[4], bfr[4];
        #pragma unroll
        for (int t4 = 0; t4 < 4; ++t4) {
            af[t4]  = *(const bf16x8*)&As[b][(wr + t4 * 16 + mrow) * 32 + quad * 8];
            bfr[t4] = *(const bf16x8*)&Bs[b][(wc + t4 * 16 + mrow) * 32 + quad * 8];
        }
        WAITLGKM0;
        BAR;
        if (k + 2 < 8) {
            const int kk = (k + 2) * 32;
            GLL(Ar0 + kk, &As[b][lds0]); GLL(Br0 + kk, &Bs[b][lds0]);
            GLL(Ar1 + kk, &As[b][lds1]); GLL(Br1 + kk, &Bs[b][lds1]);
        }
        #pragma unroll
        for (int ti = 0; ti < 4; ++ti)
            #pragma unroll
            for (int tj = 0; tj < 4; ++tj)
                acc[ti][tj] = __builtin_amdgcn_mfma_f32_16x16x32_bf16(
                                  bfr[tj], af[ti], acc[ti][tj], 0, 0, 0);
    }

    #pragma unroll
    for (int ti = 0; ti < 4; ++ti) {
        const int row = row0 + wr + ti * 16 + mrow;
        #pragma unroll
        for (int tj = 0; tj < 4; ++tj) {
            const int col = col0 + wc + tj * 16 + quad * 4;
            const float4 bv = *(const float4*)(bias + col);
            ushort4 o;
            o.x = f2b(fmaxf(acc[ti][tj][0] + bv.x, 0.f));
            o.y = f2b(fmaxf(acc[ti][tj][1] + bv.y, 0.f));
            o.z = f2b(fmaxf(acc[ti][tj][2] + bv.z, 0.f));
            o.w = f2b(fmaxf(acc[ti][tj][3] + bv.w, 0.f));
            *(ushort4*)(Cb + (size_t)row * Nout + col) = o;
        }
    }
}

// ---------------------------------------------------------------------------
// Nout=256 GEMM, 128x64 tile, async pipeline. NK = K/32 (template).
// Grid 8*4*22 swizzled. Per-iter 3 GLLs; steady in-flight 6 -> wait vmcnt(3).
// ---------------------------------------------------------------------------
template<int NK>
__global__ __launch_bounds__(256)
void gemm_n64(const unsigned short* __restrict__ A,
              const unsigned short* __restrict__ Wt,
              const float* __restrict__ bias,
              unsigned short* __restrict__ Cb)
{
    const int K = NK * 32;
    const int id  = blockIdx.x;
    const int xcd = id & 7;
    const int j   = id >> 3;
    const int c   = j & 3;
    const int r   = 8 * (j >> 2) + xcd;
    if (r >= NROWP) return;
    const int row0 = r * 128, col0 = c * 64;

    __shared__ unsigned short As[2][128 * 32];   // 16 KB
    __shared__ unsigned short Bs[2][64 * 32];    // 8 KB
    const int tid  = threadIdx.x;
    const int lane = tid & 63;
    const int wave = tid >> 6;
    const int wr = wave * 32;
    const int mrow = lane & 15, quad = lane >> 4;

    const int ri0 = tid >> 2,         ki0 = (tid & 3) * 8;
    const int ri1 = (256 + tid) >> 2, ki1 = ((256 + tid) & 3) * 8;
    const int lds0 = (wave * 64) * 8, lds1 = (256 + wave * 64) * 8;

    const unsigned short* Ar0 = A  + (size_t)(row0 + ri0) * K + ki0;
    const unsigned short* Ar1 = A  + (size_t)(row0 + ri1) * K + ki1;
    const unsigned short* Br0 = Wt + (size_t)(col0 + ri0) * K + ki0;  // rows 0..63

    f32x4 acc[2][4] = {};

    GLL(Ar0 +  0, &As[0][lds0]); GLL(Ar1 +  0, &As[0][lds1]);
    GLL(Br0 +  0, &Bs[0][lds0]);
    GLL(Ar0 + 32, &As[1][lds0]); GLL(Ar1 + 32, &As[1][lds1]);
    GLL(Br0 + 32, &Bs[1][lds0]);

    #pragma unroll
    for (int k = 0; k < NK; ++k) {
        if (k < NK - 1) WAITVM(3); else WAITVM(0);
        BAR;
        const int b = k & 1;
        bf16x8 af[2], bfr[4];
        #pragma unroll
        for (int ti = 0; ti < 2; ++ti)
            af[ti] = *(const bf16x8*)&As[b][(wr + ti * 16 + mrow) * 32 + quad * 8];
        #pragma unroll
        for (int tj = 0; tj < 4; ++tj)
            bfr[tj] = *(const bf16x8*)&Bs[b][(tj * 16 + mrow) * 32 + quad * 8];
        WAITLGKM0;
        BAR;
        if (k + 2 < NK) {
            const int kk = (k + 2) * 32;
            GLL(Ar0 + kk, &As[b][lds0]); GLL(Ar1 + kk, &As[b][lds1]);
            GLL(Br0 + kk, &Bs[b][lds0]);
        }
        #pragma unroll
        for (int ti = 0; ti < 2; ++ti)
            #pragma unroll
            for (int tj = 0; tj < 4; ++tj)
                acc[ti][tj] = __builtin_amdgcn_mfma_f32_16x16x32_bf16(
                                  bfr[tj], af[ti], acc[ti][tj], 0, 0, 0);
    }

    #pragma unroll
    for (int ti = 0; ti < 2; ++ti) {
        const int row = row0 + wr + ti * 16 + mrow;
        #pragma unroll
        for (int tj = 0; tj < 4; ++tj) {
            const int col = col0 + tj * 16 + quad * 4;
            const float4 bv = *(const float4*)(bias + col);
            ushort4 o;
            o.x = f2b(acc[ti][tj][0] + bv.x);
            o.y = f2b(acc[ti][tj][1] + bv.y);
            o.z = f2b(acc[ti][tj][2] + bv.z);
            o.w = f2b(acc[ti][tj][3] + bv.w);
            *(ushort4*)(Cb + (size_t)row * 256 + col) = o;
        }
    }
}

// ---------------------------------------------------------------------------
// Fused add + LayerNorm (D=256), one wave per row, 4 rows/block.
// ---------------------------------------------------------------------------
__global__ __launch_bounds__(256)
void addln_kernel(const unsigned short* __restrict__ c,
                  const float* __restrict__ resid_f,
                  const unsigned short* __restrict__ resid_b,
                  const float* __restrict__ g, const float* __restrict__ be,
                  float* __restrict__ out_f, unsigned short* __restrict__ out_b)
{
    const int wave = threadIdx.x >> 6;
    const int lane = threadIdx.x & 63;
    const int row  = blockIdx.x * 4 + wave;
    const size_t base = (size_t)row * 256 + (lane << 2);

    const ushort4 cu = *(const ushort4*)(c + base);
    float4 v;
    v.x = b2f(cu.x); v.y = b2f(cu.y); v.z = b2f(cu.z); v.w = b2f(cu.w);
    if (resid_f) {
        const float4 r = *(const float4*)(resid_f + base);
        v.x += r.x; v.y += r.y; v.z += r.z; v.w += r.w;
    } else {
        const ushort4 r = *(const ushort4*)(resid_b + base);
        v.x += b2f(r.x); v.y += b2f(r.y); v.z += b2f(r.z); v.w += b2f(r.w);
    }

    float s  = v.x + v.y + v.z + v.w;
    float ss = v.x * v.x + v.y * v.y + v.z * v.z + v.w * v.w;
    #pragma unroll
    for (int off = 32; off; off >>= 1) {
        s  += __shfl_xor(s, off, 64);
        ss += __shfl_xor(ss, off, 64);
    }
    const float mean = s * (1.f / 256.f);
    const float var  = ss * (1.f / 256.f) - mean * mean;
    const float rstd = rsqrtf(var + 1e-5f);

    const float4 gv = *(const float4*)(g  + (lane << 2));
    const float4 bv = *(const float4*)(be + (lane << 2));
    float4 o;
    o.x = (v.x - mean) * rstd * gv.x + bv.x;
    o.y = (v.y - mean) * rstd * gv.y + bv.y;
    o.z = (v.z - mean) * rstd * gv.z + bv.z;
    o.w = (v.w - mean) * rstd * gv.w + bv.w;
    if (out_f) *(float4*)(out_f + base) = o;
    if (out_b) {
        ushort4 u; u.x = f2b(o.x); u.y = f2b(o.y); u.z = f2b(o.z); u.w = f2b(o.w);
        *(ushort4*)(out_b + base) = u;
    }
}

// ---------------------------------------------------------------------------
// Deformable sampling. 256 threads, 8 tokens/block.
// Phase B: depth-2 software pipeline (VGPR ~36, high occupancy — measured
// faster than batched-8 gathers which cost 72 VGPR / 27% occupancy).
// ---------------------------------------------------------------------------
__global__ __launch_bounds__(256)
void sampling_kernel(const unsigned short* __restrict__ value,
                     const unsigned short* __restrict__ oa,
                     const float* __restrict__ refp,
                     unsigned short* __restrict__ samp)
{
    __shared__ unsigned s_pk[64 * 68];   // 17.4 KB
    const int t0  = blockIdx.x * 8;
    const int tid = threadIdx.x;

    #pragma unroll
    for (int rep = 0; rep < 4; ++rep) {
        const int e   = rep * 256 + tid;      // 0..1023
        const int tok = e >> 7;
        const int hp  = e & 127;
        const int h   = hp >> 4, i16 = hp & 15, l = i16 >> 2;
        const int t   = t0 + tok;

        const float ex = __expf(b2f(oa[(size_t)t * 384 + 256 + h * 16 + i16]));
        float ssum = ex;
        #pragma unroll
        for (int o = 8; o; o >>= 1) ssum += __shfl_xor(ssum, o, 16);
        const float aw = ex / ssum;

        const int   Wl_t[4]  = {64, 32, 16, 8};
        const int   LST_t[4] = {0, 4096, 5120, 5376};
        const int   Wl  = Wl_t[l];
        const int   LST = LST_t[l];
        const float fW  = (float)Wl;

        const unsigned ov = *(const unsigned*)&oa[(size_t)t * 384 + h * 32 + i16 * 2];
        const float ox = lo_bf(ov), oy = hi_bf(ov);
        const float2 rxy = *(const float2*)&refp[(size_t)t * 8 + l * 2];
        const float x = rxy.x * fW + ox - 0.5f;   // normalizer cancels (H==W per level)
        const float y = rxy.y * fW + oy - 0.5f;
        const float x0 = floorf(x), y0 = floorf(y);
        const float fx = x - x0, fy = y - y0;
        const int   ix = (int)x0, iy = (int)y0;
        const bool  vx0 = (ix >= 0) & (ix < Wl), vx1 = (ix + 1 >= 0) & (ix + 1 < Wl);

        const int base = (tok * 8 + h) * 68 + i16 * 4;
        #pragma unroll
        for (int jj = 0; jj < 2; ++jj) {              // jj = dy
            const int  yv = iy + jj;
            const bool vy = (yv >= 0) & (yv < Wl);
            const float wy = (jj ? fy : 1.f - fy) * aw;
            const int  rowi = LST + yv * Wl;
            const float w0 = (vy & vx0) ? wy * (1.f - fx) : 0.f;
            const float w1 = (vy & vx1) ? wy * fx : 0.f;
            const unsigned i0 = (vy & vx0) ? (unsigned)(rowi + ix) : 0u;
            const unsigned i1 = (vy & vx1) ? (unsigned)(rowi + ix + 1) : 0u;
            s_pk[base + jj * 2 + 0] = (i0 << 16) | f2b(w0);
            s_pk[base + jj * 2 + 1] = (i1 << 16) | f2b(w1);
        }
    }
    __syncthreads();

    const int wv_  = tid >> 6;
    const int lane = tid & 63;
    const int t2   = lane >> 5;
    const int h    = (lane >> 2) & 7;
    const int dq   = lane & 3;                 // 8-channel quad
    const int tok  = wv_ * 2 + t2;
    const int t    = t0 + tok;
    const int b    = t / NTOK;
    const char* vb = (const char*)value + ((size_t)b * NTOK * 256 + h * 32 + dq * 8) * 2;
    const unsigned* sp = s_pk + (tok * 8 + h) * 68;

    float a0 = 0.f, a1 = 0.f, a2 = 0.f, a3 = 0.f;
    float a4 = 0.f, a5 = 0.f, a6 = 0.f, a7 = 0.f;

    unsigned pkc = sp[0];
    uint4 vc = *(const uint4*)(vb + (size_t)(pkc >> 16) * 512);
    #pragma unroll 8
    for (int i = 0; i < 64; ++i) {
        unsigned pkn = 0; uint4 vn = make_uint4(0, 0, 0, 0);
        if (i < 63) {
            pkn = sp[i + 1];
            vn = *(const uint4*)(vb + (size_t)(pkn >> 16) * 512);
        }
        const float w = lo_bf(pkc);
        a0 += lo_bf(vc.x) * w; a1 += hi_bf(vc.x) * w;
        a2 += lo_bf(vc.y) * w; a3 += hi_bf(vc.y) * w;
        a4 += lo_bf(vc.z) * w; a5 += hi_bf(vc.z) * w;
        a6 += lo_bf(vc.w) * w; a7 += hi_bf(vc.w) * w;
        pkc = pkn; vc = vn;
    }
    ushort4 o0, o1;
    o0.x = f2b(a0); o0.y = f2b(a1); o0.z = f2b(a2); o0.w = f2b(a3);
    o1.x = f2b(a4); o1.y = f2b(a5); o1.z = f2b(a6); o1.w = f2b(a7);
    unsigned short* op = samp + (size_t)t * 256 + h * 32 + dq * 8;
    *(ushort4*)(op)     = o0;
    *(ushort4*)(op + 4) = o1;
}

// ---------------------------------------------------------------------------
// Prep: q_bf = bf16(src+pos), src_bf = bf16(src), plus all 6 weight cvts.
// ---------------------------------------------------------------------------
__global__ __launch_bounds__(256)
void prep_kernel(const float* __restrict__ src, const float* __restrict__ pos,
                 const float* __restrict__ wv, const float* __restrict__ woff,
                 const float* __restrict__ wattn, const float* __restrict__ wout,
                 const float* __restrict__ w1, const float* __restrict__ w2,
                 unsigned short* __restrict__ q_bf, unsigned short* __restrict__ src_bf,
                 unsigned short* __restrict__ wv_b, unsigned short* __restrict__ woa_b,
                 unsigned short* __restrict__ wout_b,
                 unsigned short* __restrict__ w1_b, unsigned short* __restrict__ w2_b)
{
    const int v = blockIdx.x * 256 + threadIdx.x;
    if (v < 1392640) {
        const float4 s = ((const float4*)src)[v];
        const float4 p = ((const float4*)pos)[v];
        ushort4 qo, so;
        qo.x = f2b(s.x + p.x); qo.y = f2b(s.y + p.y);
        qo.z = f2b(s.z + p.z); qo.w = f2b(s.w + p.w);
        so.x = f2b(s.x); so.y = f2b(s.y); so.z = f2b(s.z); so.w = f2b(s.w);
        ((ushort4*)q_bf)[v]   = qo;
        ((ushort4*)src_bf)[v] = so;
        return;
    }
    const int v2 = v - 1392640;
    const float* s; unsigned short* d; int off;
    if      (v2 <  16384) { s = wv;    d = wv_b;          off = v2; }
    else if (v2 <  32768) { s = woff;  d = woa_b;         off = v2 - 16384; }
    else if (v2 <  40960) { s = wattn; d = woa_b + 65536; off = v2 - 32768; }
    else if (v2 <  57344) { s = wout;  d = wout_b;        off = v2 - 40960; }
    else if (v2 < 122880) { s = w1;    d = w1_b;          off = v2 - 57344; }
    else                  { s = w2;    d = w2_b;          off = v2 - 122880; }
    const float4 f = ((const float4*)s)[off];
    ushort4 u; u.x = f2b(f.x); u.y = f2b(f.y); u.z = f2b(f.z); u.w = f2b(f.w);
    ((ushort4*)d)[off] = u;
}

// ---------------------------------------------------------------------------
extern "C" void kernel_launch(void* const* d_in, const int* in_sizes, int n_in,
                              void* d_out, int out_size, void* d_ws, size_t ws_size,
                              hipStream_t stream) {
    const float* src     = (const float*)d_in[0];
    const float* pos     = (const float*)d_in[1];
    const float* refp    = (const float*)d_in[2];
    const float* w_value = (const float*)d_in[3];
    const float* b_value = (const float*)d_in[4];
    const float* w_off   = (const float*)d_in[5];
    const float* b_off   = (const float*)d_in[6];
    const float* w_attn  = (const float*)d_in[7];
    const float* b_attn  = (const float*)d_in[8];
    const float* w_out   = (const float*)d_in[9];
    const float* b_out   = (const float*)d_in[10];
    const float* g1      = (const float*)d_in[11];
    const float* be1     = (const float*)d_in[12];
    const float* w1      = (const float*)d_in[13];
    const float* b1      = (const float*)d_in[14];
    const float* w2      = (const float*)d_in[15];
    const float* b2      = (const float*)d_in[16];
    const float* g2      = (const float*)d_in[17];
    const float* be2     = (const float*)d_in[18];
    const unsigned char* pmask = (const unsigned char*)d_in[21];

    // ---- workspace (~80 MB) ----
    char* ws = (char*)d_ws;
    const size_t SZ16 = (size_t)MTOT * 256 * 2;            // 11,141,120 B
    unsigned short* q_bf    = (unsigned short*)(ws);                    // [0, 11.1M)
    unsigned short* src_bf  = (unsigned short*)(ws + SZ16);             // [11.1, 22.3)
    unsigned short* value_b = (unsigned short*)(ws + 2 * SZ16);         // [22.3, 33.4)
    unsigned short* oa_b    = (unsigned short*)(ws + 3 * SZ16);         // [33.4, 50.1) MTOT*384
    unsigned short* samp    = (unsigned short*)(ws + 50135040ULL);      // [50.1, 61.3)
    unsigned short* h_bf    = (unsigned short*)(ws + 3 * SZ16);         // [33.4, 78.0) over oa+samp
    unsigned short* wts     = (unsigned short*)(ws + 77987840ULL);      // 1.6 MB
    // aliases (lifetimes disjoint):
    unsigned short* x_bf    = q_bf;      // q dead after qkv
    unsigned short* C1_bf   = value_b;   // value dead after sampling
    unsigned short* C2_bf   = src_bf;    // src_bf dead after qkv

    unsigned short* wv_b    = wts;
    unsigned short* woa_b   = wv_b   + 65536;
    unsigned short* wout_b  = woa_b  + 98304;
    unsigned short* w1_b    = wout_b + 65536;
    unsigned short* w2_b    = w1_b   + 262144;

    const dim3 blk(256);

    prep_kernel<<<dim3(6176), blk, 0, stream>>>(src, pos, w_value, w_off, w_attn,
                                                w_out, w1, w2, q_bf, src_bf,
                                                wv_b, woa_b, wout_b, w1_b, w2_b);
    // value / [off|attn]
    qkv_gemm<<<dim3(8 * 5 * 22), blk, 0, stream>>>(
        src_bf, q_bf, wv_b, woa_b, b_value, b_off, b_attn, pmask, value_b, oa_b);
    // deformable sampling -> bf16
    sampling_kernel<<<dim3(MTOT / 8), blk, 0, stream>>>(value_b, oa_b, refp, samp);
    // C1 = samp @ w_out^T + b_out
    gemm_n64<8><<<dim3(8 * 4 * 22), blk, 0, stream>>>(samp, wout_b, b_out, C1_bf);
    // x_bf = LN(src + C1)
    addln_kernel<<<dim3(MTOT / 4), blk, 0, stream>>>(
        C1_bf, src, nullptr, g1, be1, nullptr, x_bf);
    // h = relu(x @ w1^T + b1)
    ffn1_gemm<<<dim3(8 * 8 * 22), blk, 0, stream>>>(x_bf, w1_b, b1, h_bf);
    // C2 = h @ w2^T + b2
    gemm_n64<32><<<dim3(8 * 4 * 22), blk, 0, stream>>>(h_bf, w2_b, b2, C2_bf);
    // out = LN(x + C2)  (fp32)
    addln_kernel<<<dim3(MTOT / 4), blk, 0, stream>>>(
        C2_bf, nullptr, x_bf, g2, be2, (float*)d_out, nullptr);
}